// Round 8
// baseline (159.484 us; speedup 1.0000x reference)
//
#include <hip/hip_runtime.h>

#define NPATH 16384
#define DIM   8
#define NINC  (NPATH - 1)        // 16383 output rows
#define SIG   4680               // 8 + 64 + 512 + 4096
#define L1OFF 0
#define L2OFF 8
#define L3OFF 72
#define L4OFF 584
#define NCHUNK 256               // 64-increment chunks
#define CHUNK  64
#define NSUB  1024               // 16-increment sub-chunks
#define SUB   16
#define SPC   4                  // sub-chunks per chunk
#define NGRP  16
#define GSIZE 16
#define C6    0.16666666666666666f

// Per-thread register state (t in [0,256)):
//   r4[16]: level-4 rows 2t,2t+1 of [512][8] = floats L4OFF+16t..16t+15 (contiguous!)
//   r3[2]: level-3 elems 2t,2t+1
//   a1i=a1[t>>5], a2v=a2[t>>2] (consumed by L3/L4 updates)
//   a2s=a2[t] (t<64), a1s=a1[t>>3] (t<64), a1t=a1[t] (t<8) (store mapping)

__device__ __forceinline__ void zero_state(float r4[16], float r3[2],
                                           float& a1i, float& a2v,
                                           float& a2s, float& a1s, float& a1t) {
#pragma unroll
  for (int l = 0; l < 16; ++l) r4[l] = 0.f;
  r3[0] = r3[1] = 0.f;
  a1i = a2v = a2s = a1s = a1t = 0.f;
}

__device__ __forceinline__ void store_sig_reg(float* __restrict__ dst,
                                              const float r4[16], const float r3[2],
                                              float a2s, float a1t, int t) {
  float4* d4 = (float4*)(dst + L4OFF + 16 * t);
  d4[0] = make_float4(r4[0], r4[1], r4[2], r4[3]);
  d4[1] = make_float4(r4[4], r4[5], r4[6], r4[7]);
  d4[2] = make_float4(r4[8], r4[9], r4[10], r4[11]);
  d4[3] = make_float4(r4[12], r4[13], r4[14], r4[15]);
  *(float2*)(dst + L3OFF + 2 * t) = make_float2(r3[0], r3[1]);
  if (t < 64) dst[L2OFF + t] = a2s;
  if (t < 8)  dst[L1OFF + t] = a1t;
}

__device__ __forceinline__ void load_state(const float* __restrict__ src,
                                           float r4[16], float r3[2],
                                           float& a1i, float& a2v,
                                           float& a2s, float& a1s, float& a1t, int t) {
  const float4* s4 = (const float4*)(src + L4OFF + 16 * t);
  float4 G0 = s4[0], G1 = s4[1], G2 = s4[2], G3 = s4[3];
  r4[0]=G0.x; r4[1]=G0.y; r4[2]=G0.z; r4[3]=G0.w;
  r4[4]=G1.x; r4[5]=G1.y; r4[6]=G1.z; r4[7]=G1.w;
  r4[8]=G2.x; r4[9]=G2.y; r4[10]=G2.z; r4[11]=G2.w;
  r4[12]=G3.x; r4[13]=G3.y; r4[14]=G3.z; r4[15]=G3.w;
  const float2 gr3 = *(const float2*)(src + L3OFF + 2 * t);
  r3[0] = gr3.x; r3[1] = gr3.y;
  a1i = src[L1OFF + (t >> 5)];
  a2v = src[L2OFF + (t >> 2)];
  a2s = a1s = a1t = 0.f;
  if (t < 64) { a2s = src[L2OFF + t]; a1s = src[L1OFF + (t >> 3)]; }
  if (t < 8)  { a1t = src[L1OFF + t]; }
}

// ---- general Chen product a = a o b (inline loads) ----
__device__ __forceinline__ void chen_reg(float r4[16], float r3[2],
                                         float& a1i, float& a2v,
                                         float& a2s, float& a1s, float& a1t,
                                         const float* __restrict__ b, int t) {
  const int i   = t >> 5;
  const int j   = (t >> 2) & 7;
  const int ij  = t >> 2;
  const int c0  = 2 * t;
  const int jk0 = c0 & 63;
  const int k0  = 2 * (t & 3);
  const int i2  = t >> 3;
  const int j2  = t & 7;
  const float4* bv = (const float4*)b;
  float4 B0 = bv[146 + 4 * t], B1 = bv[147 + 4 * t], B2 = bv[148 + 4 * t], B3 = bv[149 + 4 * t];
  float4 Cq0 = bv[18 + 2 * jk0], Cq1 = bv[19 + 2 * jk0], Cq2 = bv[20 + 2 * jk0], Cq3 = bv[21 + 2 * jk0];
  float4 D0 = bv[2 + 2 * k0], D1 = bv[3 + 2 * k0], D2 = bv[4 + 2 * k0], D3 = bv[5 + 2 * k0];
  float4 E0 = bv[0], E1 = bv[1];
  const float2 b3c  = *(const float2*)(b + L3OFF + c0);
  const float2 b2jk = *(const float2*)(b + L2OFF + jk0);
  const float2 b1k  = *(const float2*)(b + L1OFF + k0);
  const float b2ij = b[L2OFF + ij];
  const float b1j  = b[L1OFF + j];
  const float b1i  = b[L1OFF + i];
  float b2t = 0.f, b1j2 = 0.f, b1i2 = 0.f, b1t = 0.f;
  if (t < 64) { b2t = b[L2OFF + t]; b1j2 = b[L1OFF + j2]; b1i2 = b[L1OFF + i2]; }
  if (t < 8)  { b1t = b[L1OFF + t]; }

  const float b4r[16] = {B0.x,B0.y,B0.z,B0.w, B1.x,B1.y,B1.z,B1.w,
                         B2.x,B2.y,B2.z,B2.w, B3.x,B3.y,B3.z,B3.w};
  const float b3r[16] = {Cq0.x,Cq0.y,Cq0.z,Cq0.w, Cq1.x,Cq1.y,Cq1.z,Cq1.w,
                         Cq2.x,Cq2.y,Cq2.z,Cq2.w, Cq3.x,Cq3.y,Cq3.z,Cq3.w};
  const float b2r[16] = {D0.x,D0.y,D0.z,D0.w, D1.x,D1.y,D1.z,D1.w,
                         D2.x,D2.y,D2.z,D2.w, D3.x,D3.y,D3.z,D3.w};
  const float b1r[8]  = {E0.x,E0.y,E0.z,E0.w, E1.x,E1.y,E1.z,E1.w};

#pragma unroll
  for (int l = 0; l < 8; ++l) {
    r4[l]     += b4r[l]     + a1i * b3r[l]     + a2v * b2r[l]     + r3[0] * b1r[l];
    r4[8 + l] += b4r[8 + l] + a1i * b3r[8 + l] + a2v * b2r[8 + l] + r3[1] * b1r[l];
  }
  r3[0] += b3c.x + a1i * b2jk.x + a2v * b1k.x;
  r3[1] += b3c.y + a1i * b2jk.y + a2v * b1k.y;
  const float a1i_old = a1i;
  a2v += b2ij + a1i_old * b1j;
  if (t < 64) { a2s += b2t + a1s * b1j2; a1s += b1i2; }
  a1i = a1i_old + b1i;
  if (t < 8) a1t += b1t;
}

// ---- Chen b-operand: pure-load / pure-VALU split (for pipelined scans) ----
struct ChenB {
  float4 B0, B1, B2, B3;
  float4 C0, C1, C2, C3;
  float4 D0, D1, D2, D3;
  float4 E0, E1;
  float2 b3c, b2jk, b1k;
  float  b2ij, b1j, b1i, b2t, b1j2, b1i2, b1t;
};

__device__ __forceinline__ void chen_load(const float* __restrict__ b, int t, ChenB& R) {
  const int i   = t >> 5;
  const int j   = (t >> 2) & 7;
  const int ij  = t >> 2;
  const int c0  = 2 * t;
  const int jk0 = c0 & 63;
  const int k0  = 2 * (t & 3);
  const int i2  = t >> 3;
  const int j2  = t & 7;
  const float4* bv = (const float4*)b;
  R.B0 = bv[146 + 4 * t]; R.B1 = bv[147 + 4 * t]; R.B2 = bv[148 + 4 * t]; R.B3 = bv[149 + 4 * t];
  R.C0 = bv[18 + 2 * jk0]; R.C1 = bv[19 + 2 * jk0]; R.C2 = bv[20 + 2 * jk0]; R.C3 = bv[21 + 2 * jk0];
  R.D0 = bv[2 + 2 * k0]; R.D1 = bv[3 + 2 * k0]; R.D2 = bv[4 + 2 * k0]; R.D3 = bv[5 + 2 * k0];
  R.E0 = bv[0]; R.E1 = bv[1];
  R.b3c  = *(const float2*)(b + L3OFF + c0);
  R.b2jk = *(const float2*)(b + L2OFF + jk0);
  R.b1k  = *(const float2*)(b + L1OFF + k0);
  R.b2ij = b[L2OFF + ij];
  R.b1j  = b[L1OFF + j];
  R.b1i  = b[L1OFF + i];
  R.b2t = 0.f; R.b1j2 = 0.f; R.b1i2 = 0.f; R.b1t = 0.f;
  if (t < 64) { R.b2t = b[L2OFF + t]; R.b1j2 = b[L1OFF + j2]; R.b1i2 = b[L1OFF + i2]; }
  if (t < 8)  { R.b1t = b[L1OFF + t]; }
}

__device__ __forceinline__ void chen_apply(float r4[16], float r3[2],
                                           float& a1i, float& a2v,
                                           float& a2s, float& a1s, float& a1t,
                                           const ChenB& R, int t) {
  const float b4r[16] = {R.B0.x,R.B0.y,R.B0.z,R.B0.w, R.B1.x,R.B1.y,R.B1.z,R.B1.w,
                         R.B2.x,R.B2.y,R.B2.z,R.B2.w, R.B3.x,R.B3.y,R.B3.z,R.B3.w};
  const float b3r[16] = {R.C0.x,R.C0.y,R.C0.z,R.C0.w, R.C1.x,R.C1.y,R.C1.z,R.C1.w,
                         R.C2.x,R.C2.y,R.C2.z,R.C2.w, R.C3.x,R.C3.y,R.C3.z,R.C3.w};
  const float b2r[16] = {R.D0.x,R.D0.y,R.D0.z,R.D0.w, R.D1.x,R.D1.y,R.D1.z,R.D1.w,
                         R.D2.x,R.D2.y,R.D2.z,R.D2.w, R.D3.x,R.D3.y,R.D3.z,R.D3.w};
  const float b1r[8]  = {R.E0.x,R.E0.y,R.E0.z,R.E0.w, R.E1.x,R.E1.y,R.E1.z,R.E1.w};
#pragma unroll
  for (int l = 0; l < 8; ++l) {
    r4[l]     += b4r[l]     + a1i * b3r[l]     + a2v * b2r[l]     + r3[0] * b1r[l];
    r4[8 + l] += b4r[8 + l] + a1i * b3r[8 + l] + a2v * b2r[8 + l] + r3[1] * b1r[l];
  }
  r3[0] += R.b3c.x + a1i * R.b2jk.x + a2v * R.b1k.x;
  r3[1] += R.b3c.y + a1i * R.b2jk.y + a2v * R.b1k.y;
  const float a1i_old = a1i;
  a2v += R.b2ij + a1i_old * R.b1j;
  if (t < 64) { a2s += R.b2t + a1s * R.b1j2; a1s += R.b1i2; }
  a1i = a1i_old + R.b1i;
  if (t < 8) a1t += R.b1t;
}

// ---- one exp-Chen step (Horner form), register-only ----
__device__ __forceinline__ void step_update(const float* zs,
                                            float r4[16], float r3[2],
                                            float& a1i, float& a2v,
                                            float& a2s, float& a1s, float& a1t, int t) {
  const int i  = t >> 5;
  const int j  = (t >> 2) & 7;
  const int k0 = 2 * (t & 3);
  const int i2 = t >> 3;
  const int j2 = t & 7;
  const float zi = zs[i];
  const float zj = zs[j];
  const float2 zk = *(const float2*)(zs + k0);
  const float4 za = *(const float4*)zs;
  const float4 zb = *(const float4*)(zs + 4);
  const float zn[8] = {za.x, za.y, za.z, za.w, zb.x, zb.y, zb.z, zb.w};
  const float a1zi4 = a1i + 0.25f * zi;
  const float zj6   = C6 * zj;
  const float T0 = r3[0] + a2v * (0.5f * zk.x) + a1zi4 * (zj6 * zk.x);
  const float T1 = r3[1] + a2v * (0.5f * zk.y) + a1zi4 * (zj6 * zk.y);
  const float U  = a2v + (0.5f * a1i + C6 * zi) * zj;
#pragma unroll
  for (int l = 0; l < 8; ++l) {
    r4[l]     += T0 * zn[l];
    r4[8 + l] += T1 * zn[l];
  }
  r3[0] += zk.x * U;
  r3[1] += zk.y * U;
  a2v += (a1i + 0.5f * zi) * zj;
  a1i += zi;
  if (t < 64) {
    const float zi2 = zs[i2], zj2v = zs[j2];
    a2s += (a1s + 0.5f * zi2) * zj2v;
    a1s += zi2;
  }
  if (t < 8) a1t += zs[t];
}

// ================= K1: chunk totals + intra-chunk snapshots (w=1..3) =================
__global__ __launch_bounds__(256) void k_totals(const float* __restrict__ path,
                                                float* __restrict__ T64,
                                                float* __restrict__ snap) {
  __shared__ float zbuf[CHUNK][8];
  const int t = threadIdx.x;
  const int b = blockIdx.x;
  const int base = b * CHUNK;
  for (int u = t; u < CHUNK * 8; u += 256) {
    const int s = u >> 3, l = u & 7;
    const int rB = min(base + s + 1, NPATH - 1);
    zbuf[s][l] = path[rB * DIM + l] - path[(base + s) * DIM + l];   // z=0 pad at end
  }
  float r4[16], r3[2], a1i, a2v, a2s, a1s, a1t;
  zero_state(r4, r3, a1i, a2v, a2s, a1s, a1t);
  __syncthreads();
  for (int w = 0; w < SPC; ++w) {
    if (w > 0) store_sig_reg(snap + ((size_t)b * SPC + w) * SIG, r4, r3, a2s, a1t, t);
#pragma unroll
    for (int s2 = 0; s2 < SUB; ++s2)
      step_update(zbuf[SUB * w + s2], r4, r3, a1i, a2v, a2s, a1s, a1t, t);
  }
  store_sig_reg(T64 + (size_t)b * SIG, r4, r3, a2s, a1t, t);
}

// ================= K2/K3: pipelined sequential scan (count even) =================
__global__ __launch_bounds__(256) void k_scan(const float* __restrict__ in,
                                              float* __restrict__ prefout,
                                              float* __restrict__ totout,
                                              int count) {
  const int t = threadIdx.x;
  const size_t goff = (size_t)blockIdx.x * count;
  float r4[16], r3[2], a1i, a2v, a2s, a1s, a1t;
  zero_state(r4, r3, a1i, a2v, a2s, a1s, a1t);
  ChenB bA, bB;
  chen_load(in + goff * SIG, t, bA);
  for (int m = 0; m < count; m += 2) {
    if (m + 1 < count) chen_load(in + (goff + m + 1) * SIG, t, bB);
    store_sig_reg(prefout + (goff + m) * SIG, r4, r3, a2s, a1t, t);     // exclusive
    chen_apply(r4, r3, a1i, a2v, a2s, a1s, a1t, bA, t);
    if (m + 1 >= count) break;
    if (m + 2 < count) chen_load(in + (goff + m + 2) * SIG, t, bA);
    store_sig_reg(prefout + (goff + m + 1) * SIG, r4, r3, a2s, a1t, t); // exclusive
    chen_apply(r4, r3, a1i, a2v, a2s, a1s, a1t, bB, t);
  }
  if (totout != nullptr) store_sig_reg(totout + (size_t)blockIdx.x * SIG, r4, r3, a2s, a1t, t);
}

// ================= K4: 1024 blocks x 16 rows; barrier-free store loop (A/B vs R7) ========
__global__ __launch_bounds__(256) void k_out(const float* __restrict__ path,
                                             const float* __restrict__ pref,
                                             const float* __restrict__ gpref,
                                             const float* __restrict__ snap,
                                             float* __restrict__ out) {
  __shared__ float zbuf[SUB][8];
  const int t = threadIdx.x;
  const int sIdx = blockIdx.x;
  const int b = sIdx >> 2;         // chunk64 (SPC=4)
  const int g = b >> 4;            // group
  const int base = sIdx * SUB;
  const int n = min(SUB, NINC - base);
  if (t < SUB * 8) {
    const int s = t >> 3, l = t & 7;
    const int rB = min(base + s + 1, NPATH - 1);
    zbuf[s][l] = path[rB * DIM + l] - path[(base + s) * DIM + l];
  }
  float r4[16], r3[2], a1i, a2v, a2s, a1s, a1t;
  load_state(gpref + (size_t)g * SIG, r4, r3, a1i, a2v, a2s, a1s, a1t, t);
  chen_reg(r4, r3, a1i, a2v, a2s, a1s, a1t, pref + (size_t)b * SIG, t);
  if (sIdx & 3)   // w=0 snapshot is the identity -> skip
    chen_reg(r4, r3, a1i, a2v, a2s, a1s, a1t, snap + (size_t)sIdx * SIG, t);
  __syncthreads();   // zbuf ready; no barriers after this point
  for (int s2 = 0; s2 < n; ++s2) {
    step_update(zbuf[s2], r4, r3, a1i, a2v, a2s, a1s, a1t, t);
    // direct per-thread stores: thread t owns floats L4OFF+16t..16t+15 (contiguous 64B)
    store_sig_reg(out + (size_t)(base + s2) * SIG, r4, r3, a2s, a1t, t);
  }
}

extern "C" void kernel_launch(void* const* d_in, const int* in_sizes, int n_in,
                              void* d_out, int out_size, void* d_ws, size_t ws_size,
                              hipStream_t stream) {
  (void)in_sizes; (void)n_in; (void)out_size; (void)ws_size;
  const float* path = (const float*)d_in[0];
  float* out = (float*)d_out;
  float* ws = (float*)d_ws;

  float* T64    = ws;                                 // 256 * SIG
  float* pref   = T64    + (size_t)NCHUNK * SIG;      // 256 * SIG
  float* gtot   = pref   + (size_t)NCHUNK * SIG;      // 16 * SIG
  float* gpref  = gtot   + (size_t)NGRP * SIG;        // 16 * SIG
  float* snap   = gpref  + (size_t)NGRP * SIG;        // 1024 * SIG

  k_totals<<<NCHUNK, 256, 0, stream>>>(path, T64, snap);
  k_scan<<<NGRP, 256, 0, stream>>>(T64, pref, gtot, GSIZE);
  k_scan<<<1, 256, 0, stream>>>(gtot, gpref, nullptr, NGRP);
  k_out<<<NSUB, 256, 0, stream>>>(path, pref, gpref, snap, out);
}

// Round 9
// 133.481 us; speedup vs baseline: 1.1948x; 1.1948x over previous
//
#include <hip/hip_runtime.h>

#define NPATH 16384
#define DIM   8
#define NINC  (NPATH - 1)        // 16383 output rows
#define SIG   4680               // 8 + 64 + 512 + 4096
#define L1OFF 0
#define L2OFF 8
#define L3OFF 72
#define L4OFF 584
#define NCHUNK 256               // 64-increment chunks
#define CHUNK  64
#define NSUB  1024               // 16-increment sub-chunks
#define SUB   16
#define SPC   4                  // sub-chunks per chunk
#define NGRP  16
#define GSIZE 16
#define C6    0.16666666666666666f
#define LPAD  17                 // transpose buffer stride (16 + 1 pad floats)

// Per-thread register state (t in [0,256)):
//   r4[16]: level-4 rows 2t,2t+1 of [512][8] (= floats L4OFF+16t..16t+15)
//   r3[2]: level-3 elems 2t,2t+1
//   a1i=a1[t>>5], a2v=a2[t>>2] (consumed by L3/L4 updates)
//   a2s=a2[t] (t<64), a1s=a1[t>>3] (t<64), a1t=a1[t] (t<8) (store mapping)

__device__ __forceinline__ void light_barrier() {
  asm volatile("s_waitcnt lgkmcnt(0)" ::: "memory");
  __builtin_amdgcn_s_barrier();
}

__device__ __forceinline__ void zero_state(float r4[16], float r3[2],
                                           float& a1i, float& a2v,
                                           float& a2s, float& a1s, float& a1t) {
#pragma unroll
  for (int l = 0; l < 16; ++l) r4[l] = 0.f;
  r3[0] = r3[1] = 0.f;
  a1i = a2v = a2s = a1s = a1t = 0.f;
}

__device__ __forceinline__ void store_sig_reg(float* __restrict__ dst,
                                              const float r4[16], const float r3[2],
                                              float a2s, float a1t, int t) {
  float4* d4 = (float4*)(dst + L4OFF + 16 * t);
  d4[0] = make_float4(r4[0], r4[1], r4[2], r4[3]);
  d4[1] = make_float4(r4[4], r4[5], r4[6], r4[7]);
  d4[2] = make_float4(r4[8], r4[9], r4[10], r4[11]);
  d4[3] = make_float4(r4[12], r4[13], r4[14], r4[15]);
  *(float2*)(dst + L3OFF + 2 * t) = make_float2(r3[0], r3[1]);
  if (t < 64) dst[L2OFF + t] = a2s;
  if (t < 8)  dst[L1OFF + t] = a1t;
}

__device__ __forceinline__ void load_state(const float* __restrict__ src,
                                           float r4[16], float r3[2],
                                           float& a1i, float& a2v,
                                           float& a2s, float& a1s, float& a1t, int t) {
  const float4* s4 = (const float4*)(src + L4OFF + 16 * t);
  float4 G0 = s4[0], G1 = s4[1], G2 = s4[2], G3 = s4[3];
  r4[0]=G0.x; r4[1]=G0.y; r4[2]=G0.z; r4[3]=G0.w;
  r4[4]=G1.x; r4[5]=G1.y; r4[6]=G1.z; r4[7]=G1.w;
  r4[8]=G2.x; r4[9]=G2.y; r4[10]=G2.z; r4[11]=G2.w;
  r4[12]=G3.x; r4[13]=G3.y; r4[14]=G3.z; r4[15]=G3.w;
  const float2 gr3 = *(const float2*)(src + L3OFF + 2 * t);
  r3[0] = gr3.x; r3[1] = gr3.y;
  a1i = src[L1OFF + (t >> 5)];
  a2v = src[L2OFF + (t >> 2)];
  a2s = a1s = a1t = 0.f;
  if (t < 64) { a2s = src[L2OFF + t]; a1s = src[L1OFF + (t >> 3)]; }
  if (t < 8)  { a1t = src[L1OFF + t]; }
}

// ---- Chen b-operand: pure-load / pure-VALU split ----
struct ChenB {
  float4 B0, B1, B2, B3;
  float4 C0, C1, C2, C3;
  float4 D0, D1, D2, D3;
  float4 E0, E1;
  float2 b3c, b2jk, b1k;
  float  b2ij, b1j, b1i, b2t, b1j2, b1i2, b1t;
};

__device__ __forceinline__ void chen_load(const float* __restrict__ b, int t, ChenB& R) {
  const int i   = t >> 5;
  const int j   = (t >> 2) & 7;
  const int ij  = t >> 2;
  const int c0  = 2 * t;
  const int jk0 = c0 & 63;
  const int k0  = 2 * (t & 3);
  const int i2  = t >> 3;
  const int j2  = t & 7;
  const float4* bv = (const float4*)b;
  R.B0 = bv[146 + 4 * t]; R.B1 = bv[147 + 4 * t]; R.B2 = bv[148 + 4 * t]; R.B3 = bv[149 + 4 * t];
  R.C0 = bv[18 + 2 * jk0]; R.C1 = bv[19 + 2 * jk0]; R.C2 = bv[20 + 2 * jk0]; R.C3 = bv[21 + 2 * jk0];
  R.D0 = bv[2 + 2 * k0]; R.D1 = bv[3 + 2 * k0]; R.D2 = bv[4 + 2 * k0]; R.D3 = bv[5 + 2 * k0];
  R.E0 = bv[0]; R.E1 = bv[1];
  R.b3c  = *(const float2*)(b + L3OFF + c0);
  R.b2jk = *(const float2*)(b + L2OFF + jk0);
  R.b1k  = *(const float2*)(b + L1OFF + k0);
  R.b2ij = b[L2OFF + ij];
  R.b1j  = b[L1OFF + j];
  R.b1i  = b[L1OFF + i];
  R.b2t = 0.f; R.b1j2 = 0.f; R.b1i2 = 0.f; R.b1t = 0.f;
  if (t < 64) { R.b2t = b[L2OFF + t]; R.b1j2 = b[L1OFF + j2]; R.b1i2 = b[L1OFF + i2]; }
  if (t < 8)  { R.b1t = b[L1OFF + t]; }
}

__device__ __forceinline__ void chen_apply(float r4[16], float r3[2],
                                           float& a1i, float& a2v,
                                           float& a2s, float& a1s, float& a1t,
                                           const ChenB& R, int t) {
  const float b4r[16] = {R.B0.x,R.B0.y,R.B0.z,R.B0.w, R.B1.x,R.B1.y,R.B1.z,R.B1.w,
                         R.B2.x,R.B2.y,R.B2.z,R.B2.w, R.B3.x,R.B3.y,R.B3.z,R.B3.w};
  const float b3r[16] = {R.C0.x,R.C0.y,R.C0.z,R.C0.w, R.C1.x,R.C1.y,R.C1.z,R.C1.w,
                         R.C2.x,R.C2.y,R.C2.z,R.C2.w, R.C3.x,R.C3.y,R.C3.z,R.C3.w};
  const float b2r[16] = {R.D0.x,R.D0.y,R.D0.z,R.D0.w, R.D1.x,R.D1.y,R.D1.z,R.D1.w,
                         R.D2.x,R.D2.y,R.D2.z,R.D2.w, R.D3.x,R.D3.y,R.D3.z,R.D3.w};
  const float b1r[8]  = {R.E0.x,R.E0.y,R.E0.z,R.E0.w, R.E1.x,R.E1.y,R.E1.z,R.E1.w};
#pragma unroll
  for (int l = 0; l < 8; ++l) {
    r4[l]     += b4r[l]     + a1i * b3r[l]     + a2v * b2r[l]     + r3[0] * b1r[l];
    r4[8 + l] += b4r[8 + l] + a1i * b3r[8 + l] + a2v * b2r[8 + l] + r3[1] * b1r[l];
  }
  r3[0] += R.b3c.x + a1i * R.b2jk.x + a2v * R.b1k.x;
  r3[1] += R.b3c.y + a1i * R.b2jk.y + a2v * R.b1k.y;
  const float a1i_old = a1i;
  a2v += R.b2ij + a1i_old * R.b1j;
  if (t < 64) { a2s += R.b2t + a1s * R.b1j2; a1s += R.b1i2; }
  a1i = a1i_old + R.b1i;
  if (t < 8) a1t += R.b1t;
}

// ---- one exp-Chen step (Horner form), register-only ----
__device__ __forceinline__ void step_update(const float* zs,
                                            float r4[16], float r3[2],
                                            float& a1i, float& a2v,
                                            float& a2s, float& a1s, float& a1t, int t) {
  const int i  = t >> 5;
  const int j  = (t >> 2) & 7;
  const int k0 = 2 * (t & 3);
  const int i2 = t >> 3;
  const int j2 = t & 7;
  const float zi = zs[i];
  const float zj = zs[j];
  const float2 zk = *(const float2*)(zs + k0);
  const float4 za = *(const float4*)zs;
  const float4 zb = *(const float4*)(zs + 4);
  const float zn[8] = {za.x, za.y, za.z, za.w, zb.x, zb.y, zb.z, zb.w};
  const float a1zi4 = a1i + 0.25f * zi;
  const float zj6   = C6 * zj;
  const float T0 = r3[0] + a2v * (0.5f * zk.x) + a1zi4 * (zj6 * zk.x);
  const float T1 = r3[1] + a2v * (0.5f * zk.y) + a1zi4 * (zj6 * zk.y);
  const float U  = a2v + (0.5f * a1i + C6 * zi) * zj;
#pragma unroll
  for (int l = 0; l < 8; ++l) {
    r4[l]     += T0 * zn[l];
    r4[8 + l] += T1 * zn[l];
  }
  r3[0] += zk.x * U;
  r3[1] += zk.y * U;
  a2v += (a1i + 0.5f * zi) * zj;
  a1i += zi;
  if (t < 64) {
    const float zi2 = zs[i2], zj2v = zs[j2];
    a2s += (a1s + 0.5f * zi2) * zj2v;
    a1s += zi2;
  }
  if (t < 8) a1t += zs[t];
}

// ================= K1: chunk totals + intra-chunk snapshots (w=1..3) =================
__global__ __launch_bounds__(256) void k_totals(const float* __restrict__ path,
                                                float* __restrict__ T64,
                                                float* __restrict__ snap) {
  __shared__ float zbuf[CHUNK][8];
  const int t = threadIdx.x;
  const int b = blockIdx.x;
  const int base = b * CHUNK;
  for (int u = t; u < CHUNK * 8; u += 256) {
    const int s = u >> 3, l = u & 7;
    const int rB = min(base + s + 1, NPATH - 1);
    zbuf[s][l] = path[rB * DIM + l] - path[(base + s) * DIM + l];   // z=0 pad at end
  }
  float r4[16], r3[2], a1i, a2v, a2s, a1s, a1t;
  zero_state(r4, r3, a1i, a2v, a2s, a1s, a1t);
  __syncthreads();
  for (int w = 0; w < SPC; ++w) {
    if (w > 0) store_sig_reg(snap + ((size_t)b * SPC + w) * SIG, r4, r3, a2s, a1t, t);
#pragma unroll
    for (int s2 = 0; s2 < SUB; ++s2)
      step_update(zbuf[SUB * w + s2], r4, r3, a1i, a2v, a2s, a1s, a1t, t);
  }
  store_sig_reg(T64 + (size_t)b * SIG, r4, r3, a2s, a1t, t);
}

// ================= K2: pipelined scan of each group's 16 totals -> pref + GT ==========
__global__ __launch_bounds__(256) void k_scan(const float* __restrict__ in,
                                              float* __restrict__ prefout,
                                              float* __restrict__ totout,
                                              int count) {
  const int t = threadIdx.x;
  const size_t goff = (size_t)blockIdx.x * count;
  float r4[16], r3[2], a1i, a2v, a2s, a1s, a1t;
  zero_state(r4, r3, a1i, a2v, a2s, a1s, a1t);
  ChenB bA, bB;
  chen_load(in + goff * SIG, t, bA);
  for (int m = 0; m < count; m += 2) {
    if (m + 1 < count) chen_load(in + (goff + m + 1) * SIG, t, bB);
    store_sig_reg(prefout + (goff + m) * SIG, r4, r3, a2s, a1t, t);     // exclusive
    chen_apply(r4, r3, a1i, a2v, a2s, a1s, a1t, bA, t);
    if (m + 1 >= count) break;
    if (m + 2 < count) chen_load(in + (goff + m + 2) * SIG, t, bA);
    store_sig_reg(prefout + (goff + m + 1) * SIG, r4, r3, a2s, a1t, t); // exclusive
    chen_apply(r4, r3, a1i, a2v, a2s, a1s, a1t, bB, t);
  }
  if (totout != nullptr) store_sig_reg(totout + (size_t)blockIdx.x * SIG, r4, r3, a2s, a1t, t);
}

// ================= K3: 1024 blocks x 16 rows; redundant gpref fold + unrolled stream ====
__global__ __launch_bounds__(256) void k_out(const float* __restrict__ path,
                                             const float* __restrict__ pref,
                                             const float* __restrict__ GT,
                                             const float* __restrict__ snap,
                                             float* __restrict__ out) {
  __shared__ float zbuf[SUB][8];
  __shared__ __align__(16) float lbuf[2][256 * LPAD];
  const int t = threadIdx.x;
  const int sIdx = blockIdx.x;
  const int b = sIdx >> 2;         // chunk64 (SPC=4)
  const int g = b >> 4;            // group (0..15)
  const int base = sIdx * SUB;
  const int n = min(SUB, NINC - base);
  if (t < SUB * 8) {
    const int s = t >> 3, l = t & 7;
    const int rB = min(base + s + 1, NPATH - 1);
    zbuf[s][l] = path[rB * DIM + l] - path[(base + s) * DIM + l];
  }
  // ---- prologue: state = GT_0 o ... o GT_{g-1} o pref[b] [o snap[sIdx]] ----
  float r4[16], r3[2], a1i, a2v, a2s, a1s, a1t;
  zero_state(r4, r3, a1i, a2v, a2s, a1s, a1t);
  const int cnt = g + 1 + ((sIdx & 3) ? 1 : 0);
  // operand m: m<g -> GT[m]; m==g -> pref[b]; m==g+1 -> snap[sIdx]
#define PADDR(m) ((m) < g ? GT + (size_t)(m) * SIG \
                          : ((m) == g ? pref + (size_t)b * SIG : snap + (size_t)sIdx * SIG))
  ChenB cA, cB;
  chen_load(PADDR(0), t, cA);
  for (int m = 0; m < cnt; m += 2) {
    if (m + 1 < cnt) chen_load(PADDR(m + 1), t, cB);
    chen_apply(r4, r3, a1i, a2v, a2s, a1s, a1t, cA, t);
    if (m + 1 >= cnt) break;
    if (m + 2 < cnt) chen_load(PADDR(m + 2), t, cA);
    chen_apply(r4, r3, a1i, a2v, a2s, a1s, a1t, cB, t);
  }
#undef PADDR
  __syncthreads();   // zbuf ready
  // ---- steady loop: unroll 4 (rename store temps -> deep store pipeline), dbuf, 1 barrier
  const int tp = t >> 2;
  const int rq = 4 * (t & 3);
#pragma unroll 4
  for (int s2 = 0; s2 < n; ++s2) {
    step_update(zbuf[s2], r4, r3, a1i, a2v, a2s, a1s, a1t, t);
    float* lb = lbuf[s2 & 1] + LPAD * t;
    *(float4*)(lb + 0)  = make_float4(r4[0], r4[1], r4[2], r4[3]);
    *(float4*)(lb + 4)  = make_float4(r4[4], r4[5], r4[6], r4[7]);
    *(float4*)(lb + 8)  = make_float4(r4[8], r4[9], r4[10], r4[11]);
    *(float4*)(lb + 12) = make_float4(r4[12], r4[13], r4[14], r4[15]);
    light_barrier();
    const float* lbr = lbuf[s2 & 1];
    float* dst = out + (size_t)(base + s2) * SIG;
#pragma unroll
    for (int q = 0; q < 4; ++q) {
      const float4 v = *(const float4*)(lbr + LPAD * (tp + 64 * q) + rq);
      *(float4*)(dst + L4OFF + 4 * t + 1024 * q) = v;   // wave-contiguous 1 KB
    }
    *(float2*)(dst + L3OFF + 2 * t) = make_float2(r3[0], r3[1]);
    if (t < 64) dst[L2OFF + t] = a2s;
    if (t < 8)  dst[L1OFF + t] = a1t;
  }
}

extern "C" void kernel_launch(void* const* d_in, const int* in_sizes, int n_in,
                              void* d_out, int out_size, void* d_ws, size_t ws_size,
                              hipStream_t stream) {
  (void)in_sizes; (void)n_in; (void)out_size; (void)ws_size;
  const float* path = (const float*)d_in[0];
  float* out = (float*)d_out;
  float* ws = (float*)d_ws;

  float* T64    = ws;                                 // 256 * SIG
  float* pref   = T64    + (size_t)NCHUNK * SIG;      // 256 * SIG
  float* GT     = pref   + (size_t)NCHUNK * SIG;      // 16 * SIG
  float* snap   = GT     + (size_t)NGRP * SIG;        // 1024 * SIG

  k_totals<<<NCHUNK, 256, 0, stream>>>(path, T64, snap);
  k_scan<<<NGRP, 256, 0, stream>>>(T64, pref, GT, GSIZE);
  k_out<<<NSUB, 256, 0, stream>>>(path, pref, GT, snap, out);
}